// Round 12
// baseline (232.042 us; speedup 1.0000x reference)
//
#include <hip/hip_runtime.h>

#define NB 4
#define CCH 256
#define NN 4096
#define DD 32

typedef __attribute__((ext_vector_type(8))) short bf16x8;
typedef __attribute__((ext_vector_type(8))) _Float16 f16x8;
typedef __attribute__((ext_vector_type(4))) _Float16 f16x4;
typedef __attribute__((ext_vector_type(2))) __fp16 fp16x2;
typedef __attribute__((ext_vector_type(4))) float f32x4;

#define MFB(a,b,c) __builtin_amdgcn_mfma_f32_16x16x32_bf16(a,b,c,0,0,0)
#define MFH(a,b,c) __builtin_amdgcn_mfma_f32_16x16x32_f16(a,b,c,0,0,0)
#define MFH16(a,b,c) __builtin_amdgcn_mfma_f32_16x16x16f16(a,b,c,0,0,0)
#define L2E 1.44269504f

__device__ inline unsigned short f2bf(float f){
    union { float f; unsigned u; } v; v.f = f;
    unsigned r = v.u + 0x7fffu + ((v.u >> 16) & 1u);
    return (unsigned short)(r >> 16);
}
__device__ inline float bfval(unsigned short h){
    union { unsigned u; float f; } v; v.u = ((unsigned)h) << 16; return v.f;
}
// native transcendental: D = 2^S0 (exactly what SL-folded softmax needs)
__device__ inline float vexp2(float x){
    float r; asm("v_exp_f32 %0, %1" : "=v"(r) : "v"(x)); return r;
}
__device__ inline f16x4 pk4(float p0, float p1, float p2, float p3){
    union { fp16x2 h2[2]; f16x4 v; } u;
    u.h2[0] = __builtin_amdgcn_cvt_pkrtz(p0, p1);
    u.h2[1] = __builtin_amdgcn_cvt_pkrtz(p2, p3);
    return u.v;
}

// ---------------------------------------------------------------- proj_qk
// q output = SINGLE f16 (QK error from q-rounding ~2e-3 typ, inside budget);
// k output = f16 hi/lo pair (k frags persist in attn registers, hi/lo there
// is free) -> attn QK = 2 MFMA instead of 3, q traffic halved.
__global__ __launch_bounds__(256) void proj_qk(
    const float* __restrict__ x,
    const float* __restrict__ wq, const float* __restrict__ bq,
    const float* __restrict__ wk, const float* __restrict__ bk,
    _Float16* __restrict__ q16,
    _Float16* __restrict__ k_hi, _Float16* __restrict__ k_lo)
{
    const int t = threadIdx.x;
    const int w = t >> 6;
    const int l = t & 63;
    const int lr = l & 15, lg = l >> 4;
    const int nb = blockIdx.x;
    const int b  = blockIdx.y;
    const int n0 = nb*64 + w*16;
    const int n  = n0 + lr;

    const float* xb = x + (size_t)b*CCH*NN;

    f32x4 acc[4] = {};

    for (int kc = 0; kc < 8; kc++) {
        const int cbase = kc*32 + lg*8;
        float xv[8];
        #pragma unroll
        for (int e = 0; e < 8; e++)
            xv[e] = xb[(size_t)(cbase + e)*NN + n];
        bf16x8 xh, xl;
        #pragma unroll
        for (int e = 0; e < 8; e++) {
            unsigned short h = f2bf(xv[e]);
            xh[e] = (short)h;
            xl[e] = (short)f2bf(xv[e] - bfval(h));
        }
        #pragma unroll
        for (int f = 0; f < 4; f++) {
            const float* wrow = (f < 2) ? (wq + (size_t)(f*16 + lr)*CCH)
                                        : (wk + (size_t)((f-2)*16 + lr)*CCH);
            float4 a4 = *(const float4*)(wrow + cbase);
            float4 b4 = *(const float4*)(wrow + cbase + 4);
            float wv8[8] = {a4.x,a4.y,a4.z,a4.w,b4.x,b4.y,b4.z,b4.w};
            bf16x8 wh, wl;
            #pragma unroll
            for (int e = 0; e < 8; e++) {
                unsigned short h = f2bf(wv8[e]);
                wh[e] = (short)h;
                wl[e] = (short)f2bf(wv8[e] - bfval(h));
            }
            acc[f] = MFB(xh, wl, acc[f]);
            acc[f] = MFB(xl, wh, acc[f]);
            acc[f] = MFB(xh, wh, acc[f]);
        }
    }

    #pragma unroll
    for (int f = 0; f < 4; f++) {
        const int d = (f & 1)*16 + lr;
        const bool isq = (f < 2);
        float bias = isq ? bq[d] : bk[d];
        #pragma unroll
        for (int r = 0; r < 4; r++) {
            int nn = n0 + lg*4 + r;
            float val = acc[f][r] + bias;
            size_t a = ((size_t)(b*NN + nn))*DD + d;
            if (isq) {
                q16[a] = (_Float16)val;
            } else {
                _Float16 h = (_Float16)val;
                k_hi[a] = h;
                k_lo[a] = (_Float16)(val - (float)h);
            }
        }
    }
}

// ---------------------------------------------------------------- proj_v
// Output layout BLOCKED: v16[b][ib=n/8][c][8] (f16), 16B per (ib,c) chunk.
__global__ __launch_bounds__(512) void proj_v(
    const float* __restrict__ x,
    const float* __restrict__ wv, const float* __restrict__ bv,
    _Float16* __restrict__ v16)
{
    const int t = threadIdx.x;
    const int w = t >> 6;
    const int cg = w >> 2;
    const int ng = w & 3;
    const int l = t & 63;
    const int lr = l & 15, lg = l >> 4;
    const int ob = blockIdx.x;
    const int nb = blockIdx.y;
    const int b  = blockIdx.z;
    const int n0 = nb*64 + ng*16;
    const int n  = n0 + lr;
    const int cbase0 = ob*128 + cg*64;

    const float* xb = x + (size_t)b*CCH*NN;

    f32x4 acc[4] = {};

    for (int kc = 0; kc < 8; kc++) {
        const int kbase = kc*32 + lg*8;
        float xv[8];
        #pragma unroll
        for (int e = 0; e < 8; e++)
            xv[e] = xb[(size_t)(kbase + e)*NN + n];
        bf16x8 xh, xl;
        #pragma unroll
        for (int e = 0; e < 8; e++) {
            unsigned short h = f2bf(xv[e]);
            xh[e] = (short)h;
            xl[e] = (short)f2bf(xv[e] - bfval(h));
        }
        #pragma unroll
        for (int f = 0; f < 4; f++) {
            const float* wrow = wv + (size_t)(cbase0 + f*16 + lr)*CCH;
            float4 a4 = *(const float4*)(wrow + kbase);
            float4 b4 = *(const float4*)(wrow + kbase + 4);
            float wv8[8] = {a4.x,a4.y,a4.z,a4.w,b4.x,b4.y,b4.z,b4.w};
            bf16x8 wh, wl;
            #pragma unroll
            for (int e = 0; e < 8; e++) {
                unsigned short h = f2bf(wv8[e]);
                wh[e] = (short)h;
                wl[e] = (short)f2bf(wv8[e] - bfval(h));
            }
            acc[f] = MFB(wl, xh, acc[f]);
            acc[f] = MFB(wh, xl, acc[f]);
            acc[f] = MFB(wh, xh, acc[f]);
        }
    }

    const size_t bslice = (size_t)b*(NN/8);
    #pragma unroll
    for (int f = 0; f < 4; f++) {
        #pragma unroll
        for (int r = 0; r < 4; r++) {
            int c = cbase0 + f*16 + lg*4 + r;
            float val = acc[f][r] + bv[c];
            v16[(((bslice + (n >> 3))*CCH + c) << 3) + (n & 7)] = (_Float16)val;
        }
    }
}

// ---------------------------------------------------------------- stats
// q single f16, k hi/lo f16 -> 2 MFMA per (f, j-step) instead of 3.
__global__ __launch_bounds__(512) void stats_kernel(
    const _Float16* __restrict__ q16,
    const _Float16* __restrict__ kh, const _Float16* __restrict__ kl,
    float* __restrict__ Zp)
{
    __shared__ float zW[8][64];
    const int t = threadIdx.x;
    const int w = t >> 6;
    const int l = t & 63;
    const int lr = l & 15, lg = l >> 4;
    const int it = blockIdx.x;   // 0..63 : i-tile
    const int jc = blockIdx.y;   // 0..1  : j-half (2048 j each)
    const int b  = blockIdx.z;
    const int ibase = it*64;
    const f32x4 zero = {0.f,0.f,0.f,0.f};

    f16x8 qf[4];
    #pragma unroll
    for (int f = 0; f < 4; f++) {
        size_t a = ((size_t)(b*NN + ibase + f*16 + lr))*DD + lg*8;
        qf[f] = *(const f16x8*)(q16 + a);
    }
    float Z[4] = {0.f, 0.f, 0.f, 0.f};

    const size_t k0 = ((size_t)(b*NN + jc*2048 + w*16 + lr))*DD + lg*8;
    const _Float16* kp  = kh + k0;
    const _Float16* klp = kl + k0;

    for (int jt = 0; jt < 16; ++jt) {
        f16x8 kh2 = *(const f16x8*)kp;
        f16x8 kl2 = *(const f16x8*)klp;
        #pragma unroll
        for (int f = 0; f < 4; f++) {
            f32x4 e = MFH(kl2, qf[f], zero);
            e = MFH(kh2, qf[f], e);
            Z[f] += vexp2(e[0]*L2E) + vexp2(e[1]*L2E)
                  + vexp2(e[2]*L2E) + vexp2(e[3]*L2E);
        }
        kp  += 128*DD;
        klp += 128*DD;
    }
    #pragma unroll
    for (int f = 0; f < 4; f++) {
        Z[f] += __shfl_xor(Z[f], 16, 64);
        Z[f] += __shfl_xor(Z[f], 32, 64);
        if (lg == 0) zW[w][f*16 + lr] = Z[f];
    }
    __syncthreads();
    if (t < 64) {
        float z = 0.f;
        #pragma unroll
        for (int w2 = 0; w2 < 8; ++w2) z += zW[w2][t];
        Zp[((size_t)jc*NB + b)*NN + ibase + t] = z;
    }
}

// ---------------------------------------------------------------- combine
__global__ __launch_bounds__(256) void combine_kernel(
    const float* __restrict__ Zp, float* __restrict__ Sx)
{
    const int idx = blockIdx.x*256 + threadIdx.x;   // b*NN + i, 16384 total
    Sx[idx] = log2f(Zp[idx] + Zp[(size_t)NB*NN + idx]);
}

// ---------------------------------------------------------------- attn
// R25 (from R23+R24 evidence: prefetch neutral -> not latency-bound;
// R24 doubled TLP AND doubled L2 traffic -> MFMA/VALU busy-times
// unchanged, +32us pure stall -> traffic hurt, TLP untested in
// isolation. This round raises TLP at CONSTANT traffic).
// Structure: 8 waves (512 thr) = 4 j-waves (Jw=16) x 2 i-halves.
// The 4 j-waves of an i-half group issue IDENTICAL q/s/V addresses
// every step (only K-frags differ) -> one L2 fill serves 4 waves via
// L1. Total MFMA/exp work and L2 traffic identical to R22; per-wave
// state ~85 regs -> 4 waves/SIMD (launch_bounds(512,4)).
// Grid 512 = 64 jt x 8 (b,ct) slices; 2 blocks/CU = 16 waves/CU.
// Zero barriers in main loop; one barrier + 32KB LDS i-half reduce.
// acc[8] indexed by cf only (all static -- rule #20 discipline).
__global__ __launch_bounds__(512, 4) void attn_kernel(
    const _Float16* __restrict__ q16,
    const _Float16* __restrict__ kh16, const _Float16* __restrict__ kl16,
    const _Float16* __restrict__ v16,
    const float* __restrict__ Sx,
    const float* __restrict__ x, const float* __restrict__ gamma,
    float* __restrict__ out)
{
    __shared__ __align__(16) f32x4 Rb[2048];   // 32KB i-half reduce buffer

    const int t = threadIdx.x;
    const int w = t >> 6;
    const int jw = w & 3;        // j-wave 0..3 (owns j-frag jw)
    const int ih = w >> 2;       // i-half 0..1
    const int l = t & 63;
    const int lr = l & 15, lg = l >> 4;

    // XCD slice: lin&7 = (b,ct) -> one slice per XCD (~1.8MB, L2-resident).
    const int lin = blockIdx.x;
    const int slice = lin & 7;
    const int b   = slice >> 1;
    const int ct  = slice & 1;
    const int jt  = lin >> 3;    // 0..63
    const int jbase = jt*64, cbase = ct*128;

    // K B-fragment: single j-frag jw, f16 hi/lo (persistent; 8 VGPR)
    f16x8 kfh, kfl;
    {
        size_t a = ((size_t)(b*NN + jbase + jw*16 + lr))*DD + lg*8;
        kfh = *(const f16x8*)(kh16 + a);
        kfl = *(const f16x8*)(kl16 + a);
    }

    const float* Sb = Sx + (size_t)b*NN;
    const _Float16* vb = v16 + (size_t)b*(NN/8)*CCH*8;

    const int i0 = ih*2048;     // this group's i-half; 128 steps of 16

    // identical addresses across the 4 j-waves of this i-half group
    const _Float16* qp = q16 + ((size_t)(b*NN + i0 + lr))*DD + lg*8;
    const float* sp = Sb + i0 + lg*4;
    const _Float16* vp = vb + (((size_t)(i0/8 + (lg>>1))*CCH + cbase + lr) << 3)
                            + 4*(lg & 1);

    f32x4 acc[8] = {};   // [cf] -- ONLY static subscripts!

    #pragma clang loop unroll(disable)
    for (int s = 0; s < 128; ++s) {
        // loads for THIS step (same addrs across 4 j-waves -> L1 broadcast)
        f16x8 qv = *(const f16x8*)qp;   qp += 16*DD;
        float4 s4 = *(const float4*)sp; sp += 16;
        f16x4 vv[8];
        #pragma unroll
        for (int cf = 0; cf < 8; cf++)
            vv[cf] = *(const f16x4*)(vp + cf*128);
        vp += 16*CCH;

        // QK (2 MFMA) + exp + pack: pa is directly the K=16 PV A-fragment
        f32x4 e = {};
        e = MFH(qv, kfl, e);
        e = MFH(qv, kfh, e);
        f16x4 pa = pk4(vexp2(fmaf(e[0], L2E, -s4.x)),
                       vexp2(fmaf(e[1], L2E, -s4.y)),
                       vexp2(fmaf(e[2], L2E, -s4.z)),
                       vexp2(fmaf(e[3], L2E, -s4.w)));

        __builtin_amdgcn_s_setprio(1);
        #pragma unroll
        for (int cf = 0; cf < 8; cf++)
            acc[cf] = MFH16(pa, vv[cf], acc[cf]);
        __builtin_amdgcn_s_setprio(0);
    }

    // ------------- i-half reduce (one barrier) -------------
    // slot(jw,cf) = (jw*8+cf)<<6 | lane
    if (ih == 1) {
        #pragma unroll
        for (int cf = 0; cf < 8; cf++)
            Rb[((jw*8 + cf) << 6) + l] = acc[cf];
    }
    __syncthreads();

    if (ih == 0) {
        const float gam = gamma[0];
        #pragma unroll
        for (int cf = 0; cf < 8; cf++) {
            f32x4 o = Rb[((jw*8 + cf) << 6) + l];
            f32x4 a = acc[cf];
            a[0]+=o[0]; a[1]+=o[1]; a[2]+=o[2]; a[3]+=o[3];
            const int c = cbase + cf*16 + lr;
            const int j = jbase + jw*16 + lg*4;
            size_t off = ((size_t)(b*CCH + c))*NN + j;
            float4 xv = *(const float4*)(x + off);
            float4 ov;
            ov.x = fmaf(gam, a[0], xv.x);
            ov.y = fmaf(gam, a[1], xv.y);
            ov.z = fmaf(gam, a[2], xv.z);
            ov.w = fmaf(gam, a[3], xv.w);
            *(float4*)(out + off) = ov;
        }
    }
}

// ---------------------------------------------------------------- launch
extern "C" void kernel_launch(void* const* d_in, const int* in_sizes, int n_in,
                              void* d_out, int out_size, void* d_ws, size_t ws_size,
                              hipStream_t stream)
{
    (void)in_sizes; (void)n_in; (void)out_size; (void)ws_size;
    const float* x     = (const float*)d_in[0];
    const float* wq    = (const float*)d_in[1];
    const float* bq    = (const float*)d_in[2];
    const float* wk    = (const float*)d_in[3];
    const float* bk    = (const float*)d_in[4];
    const float* wv    = (const float*)d_in[5];
    const float* bv    = (const float*)d_in[6];
    const float* gamma = (const float*)d_in[7];
    float* out = (float*)d_out;

    char* ws = (char*)d_ws;
    _Float16* q16  = (_Float16*)(ws + 0x000000);  // 1MB (f16 single)
    _Float16* k_hi = (_Float16*)(ws + 0x100000);  // 1MB (f16 hi)
    _Float16* k_lo = (_Float16*)(ws + 0x200000);  // 1MB (f16 lo)
    _Float16* v16  = (_Float16*)(ws + 0x400000);  // 8MB blocked
    float*    Zp   = (float*)   (ws + 0xC00000);  // 128KB partials
    float*    Sx   = (float*)   (ws + 0xC20000);  // 64KB (SL)

    proj_qk<<<dim3(64, 4),    256, 0, stream>>>(x, wq, bq, wk, bk,
                                                q16, k_hi, k_lo);
    proj_v <<<dim3(2, 64, 4), 512, 0, stream>>>(x, wv, bv, v16);
    stats_kernel  <<<dim3(64, 2, 4), 512, 0, stream>>>(q16, k_hi, k_lo, Zp);
    combine_kernel<<<dim3(64),       256, 0, stream>>>(Zp, Sx);
    attn_kernel   <<<dim3(512),      512, 0, stream>>>(
        q16, k_hi, k_lo, v16, Sx, x, gamma, out);
}

// Round 13
// 118.612 us; speedup vs baseline: 1.9563x; 1.9563x over previous
//
#include <hip/hip_runtime.h>

#define NB 4
#define CCH 256
#define NN 4096
#define DD 32

typedef __attribute__((ext_vector_type(8))) short bf16x8;
typedef __attribute__((ext_vector_type(8))) _Float16 f16x8;
typedef __attribute__((ext_vector_type(4))) _Float16 f16x4;
typedef __attribute__((ext_vector_type(2))) __fp16 fp16x2;
typedef __attribute__((ext_vector_type(4))) float f32x4;

#define MFB(a,b,c) __builtin_amdgcn_mfma_f32_16x16x32_bf16(a,b,c,0,0,0)
#define MFH(a,b,c) __builtin_amdgcn_mfma_f32_16x16x32_f16(a,b,c,0,0,0)
#define L2E 1.44269504f

__device__ inline unsigned short f2bf(float f){
    union { float f; unsigned u; } v; v.f = f;
    unsigned r = v.u + 0x7fffu + ((v.u >> 16) & 1u);
    return (unsigned short)(r >> 16);
}
__device__ inline float bfval(unsigned short h){
    union { unsigned u; float f; } v; v.u = ((unsigned)h) << 16; return v.f;
}
// native transcendental: D = 2^S0 (exactly what SL-folded softmax needs)
__device__ inline float vexp2(float x){
    float r; asm("v_exp_f32 %0, %1" : "=v"(r) : "v"(x)); return r;
}
__device__ inline f16x4 pk4(float p0, float p1, float p2, float p3){
    union { fp16x2 h2[2]; f16x4 v; } u;
    u.h2[0] = __builtin_amdgcn_cvt_pkrtz(p0, p1);
    u.h2[1] = __builtin_amdgcn_cvt_pkrtz(p2, p3);
    return u.v;
}

// ---------------------------------------------------------------- proj_qk
// q output = SINGLE f16 (QK error from q-rounding ~2e-3 typ, inside budget);
// k output = f16 hi/lo pair (k frags persist in attn registers, hi/lo there
// is free) -> attn QK = 2 MFMA instead of 3, q traffic halved.
__global__ __launch_bounds__(256) void proj_qk(
    const float* __restrict__ x,
    const float* __restrict__ wq, const float* __restrict__ bq,
    const float* __restrict__ wk, const float* __restrict__ bk,
    _Float16* __restrict__ q16,
    _Float16* __restrict__ k_hi, _Float16* __restrict__ k_lo)
{
    const int t = threadIdx.x;
    const int w = t >> 6;
    const int l = t & 63;
    const int lr = l & 15, lg = l >> 4;
    const int nb = blockIdx.x;
    const int b  = blockIdx.y;
    const int n0 = nb*64 + w*16;
    const int n  = n0 + lr;

    const float* xb = x + (size_t)b*CCH*NN;

    f32x4 acc[4] = {};

    for (int kc = 0; kc < 8; kc++) {
        const int cbase = kc*32 + lg*8;
        float xv[8];
        #pragma unroll
        for (int e = 0; e < 8; e++)
            xv[e] = xb[(size_t)(cbase + e)*NN + n];
        bf16x8 xh, xl;
        #pragma unroll
        for (int e = 0; e < 8; e++) {
            unsigned short h = f2bf(xv[e]);
            xh[e] = (short)h;
            xl[e] = (short)f2bf(xv[e] - bfval(h));
        }
        #pragma unroll
        for (int f = 0; f < 4; f++) {
            const float* wrow = (f < 2) ? (wq + (size_t)(f*16 + lr)*CCH)
                                        : (wk + (size_t)((f-2)*16 + lr)*CCH);
            float4 a4 = *(const float4*)(wrow + cbase);
            float4 b4 = *(const float4*)(wrow + cbase + 4);
            float wv8[8] = {a4.x,a4.y,a4.z,a4.w,b4.x,b4.y,b4.z,b4.w};
            bf16x8 wh, wl;
            #pragma unroll
            for (int e = 0; e < 8; e++) {
                unsigned short h = f2bf(wv8[e]);
                wh[e] = (short)h;
                wl[e] = (short)f2bf(wv8[e] - bfval(h));
            }
            acc[f] = MFB(xh, wl, acc[f]);
            acc[f] = MFB(xl, wh, acc[f]);
            acc[f] = MFB(xh, wh, acc[f]);
        }
    }

    #pragma unroll
    for (int f = 0; f < 4; f++) {
        const int d = (f & 1)*16 + lr;
        const bool isq = (f < 2);
        float bias = isq ? bq[d] : bk[d];
        #pragma unroll
        for (int r = 0; r < 4; r++) {
            int nn = n0 + lg*4 + r;
            float val = acc[f][r] + bias;
            size_t a = ((size_t)(b*NN + nn))*DD + d;
            if (isq) {
                q16[a] = (_Float16)val;
            } else {
                _Float16 h = (_Float16)val;
                k_hi[a] = h;
                k_lo[a] = (_Float16)(val - (float)h);
            }
        }
    }
}

// ---------------------------------------------------------------- proj_v
// Output layout BLOCKED: v16[b][ib=n/8][c][8] (f16), 16B per (ib,c) chunk.
__global__ __launch_bounds__(512) void proj_v(
    const float* __restrict__ x,
    const float* __restrict__ wv, const float* __restrict__ bv,
    _Float16* __restrict__ v16)
{
    const int t = threadIdx.x;
    const int w = t >> 6;
    const int cg = w >> 2;
    const int ng = w & 3;
    const int l = t & 63;
    const int lr = l & 15, lg = l >> 4;
    const int ob = blockIdx.x;
    const int nb = blockIdx.y;
    const int b  = blockIdx.z;
    const int n0 = nb*64 + ng*16;
    const int n  = n0 + lr;
    const int cbase0 = ob*128 + cg*64;

    const float* xb = x + (size_t)b*CCH*NN;

    f32x4 acc[4] = {};

    for (int kc = 0; kc < 8; kc++) {
        const int kbase = kc*32 + lg*8;
        float xv[8];
        #pragma unroll
        for (int e = 0; e < 8; e++)
            xv[e] = xb[(size_t)(kbase + e)*NN + n];
        bf16x8 xh, xl;
        #pragma unroll
        for (int e = 0; e < 8; e++) {
            unsigned short h = f2bf(xv[e]);
            xh[e] = (short)h;
            xl[e] = (short)f2bf(xv[e] - bfval(h));
        }
        #pragma unroll
        for (int f = 0; f < 4; f++) {
            const float* wrow = wv + (size_t)(cbase0 + f*16 + lr)*CCH;
            float4 a4 = *(const float4*)(wrow + kbase);
            float4 b4 = *(const float4*)(wrow + kbase + 4);
            float wv8[8] = {a4.x,a4.y,a4.z,a4.w,b4.x,b4.y,b4.z,b4.w};
            bf16x8 wh, wl;
            #pragma unroll
            for (int e = 0; e < 8; e++) {
                unsigned short h = f2bf(wv8[e]);
                wh[e] = (short)h;
                wl[e] = (short)f2bf(wv8[e] - bfval(h));
            }
            acc[f] = MFB(wl, xh, acc[f]);
            acc[f] = MFB(wh, xl, acc[f]);
            acc[f] = MFB(wh, xh, acc[f]);
        }
    }

    const size_t bslice = (size_t)b*(NN/8);
    #pragma unroll
    for (int f = 0; f < 4; f++) {
        #pragma unroll
        for (int r = 0; r < 4; r++) {
            int c = cbase0 + f*16 + lg*4 + r;
            float val = acc[f][r] + bv[c];
            v16[(((bslice + (n >> 3))*CCH + c) << 3) + (n & 7)] = (_Float16)val;
        }
    }
}

// ---------------------------------------------------------------- stats
// q single f16, k hi/lo f16 -> 2 MFMA per (f, j-step) instead of 3.
__global__ __launch_bounds__(512) void stats_kernel(
    const _Float16* __restrict__ q16,
    const _Float16* __restrict__ kh, const _Float16* __restrict__ kl,
    float* __restrict__ Zp)
{
    __shared__ float zW[8][64];
    const int t = threadIdx.x;
    const int w = t >> 6;
    const int l = t & 63;
    const int lr = l & 15, lg = l >> 4;
    const int it = blockIdx.x;   // 0..63 : i-tile
    const int jc = blockIdx.y;   // 0..1  : j-half (2048 j each)
    const int b  = blockIdx.z;
    const int ibase = it*64;
    const f32x4 zero = {0.f,0.f,0.f,0.f};

    f16x8 qf[4];
    #pragma unroll
    for (int f = 0; f < 4; f++) {
        size_t a = ((size_t)(b*NN + ibase + f*16 + lr))*DD + lg*8;
        qf[f] = *(const f16x8*)(q16 + a);
    }
    float Z[4] = {0.f, 0.f, 0.f, 0.f};

    const size_t k0 = ((size_t)(b*NN + jc*2048 + w*16 + lr))*DD + lg*8;
    const _Float16* kp  = kh + k0;
    const _Float16* klp = kl + k0;

    for (int jt = 0; jt < 16; ++jt) {
        f16x8 kh2 = *(const f16x8*)kp;
        f16x8 kl2 = *(const f16x8*)klp;
        #pragma unroll
        for (int f = 0; f < 4; f++) {
            f32x4 e = MFH(kl2, qf[f], zero);
            e = MFH(kh2, qf[f], e);
            Z[f] += vexp2(e[0]*L2E) + vexp2(e[1]*L2E)
                  + vexp2(e[2]*L2E) + vexp2(e[3]*L2E);
        }
        kp  += 128*DD;
        klp += 128*DD;
    }
    #pragma unroll
    for (int f = 0; f < 4; f++) {
        Z[f] += __shfl_xor(Z[f], 16, 64);
        Z[f] += __shfl_xor(Z[f], 32, 64);
        if (lg == 0) zW[w][f*16 + lr] = Z[f];
    }
    __syncthreads();
    if (t < 64) {
        float z = 0.f;
        #pragma unroll
        for (int w2 = 0; w2 < 8; ++w2) z += zW[w2][t];
        Zp[((size_t)jc*NB + b)*NN + ibase + t] = z;
    }
}

// ---------------------------------------------------------------- combine
__global__ __launch_bounds__(256) void combine_kernel(
    const float* __restrict__ Zp, float* __restrict__ Sx)
{
    const int idx = blockIdx.x*256 + threadIdx.x;   // b*NN + i, 16384 total
    Sx[idx] = log2f(Zp[idx] + Zp[(size_t)NB*NN + idx]);
}

// ---------------------------------------------------------------- attn
// R26 (from R21-R25 evidence: MFMA busy-time INVARIANT at ~36us across 5
// structural variants. Rate check: total 5.16e13 MFMA FLOP = 20.6us at
// 2.5PF -- but if mfma_16x16x16_f16 (our PV) issues in the SAME cycles
// as the K=32 form (gfx950 doubled K at constant cost; K=16 is the
// legacy half-rate shape), predicted busy = 34.4us == measured. PV was
// wasting HALF the matrix pipe).
// Change: PV -> mfma_f32_16x16x32_f16 via sigma-PERMUTED QK row mapping:
// step A loads q rows 8(lr>>2)+(lr&3), step B +4 -> step A C-frag holds
// P[j=lr][i=8lg+0..3], step B [8lg+4..7]; concat of the two packed
// f16x4s IS the K=32 A-fragment -- zero shuffles, just addressing.
// S follows sigma (float4 at 8lg/8lg+4); V B-frag = one 16B v16 block.
// PV MFMA count halves (64->32 per 32-i); QK/exp/traffic unchanged.
// Structure otherwise identical to R22 (best: 73.7us).
__global__ __launch_bounds__(256, 2) void attn_kernel(
    const _Float16* __restrict__ q16,
    const _Float16* __restrict__ kh16, const _Float16* __restrict__ kl16,
    const _Float16* __restrict__ v16,
    const float* __restrict__ Sx,
    const float* __restrict__ x, const float* __restrict__ gamma,
    float* __restrict__ out)
{
    __shared__ __align__(16) f32x4 Rb[4096];   // 64KB end-reduce buffer

    const int t = threadIdx.x;
    const int wv = t >> 6;       // i-quarter 0..3
    const int l = t & 63;
    const int lr = l & 15, lg = l >> 4;

    // XCD slice: lin&7 = (b,ct) -> one slice per XCD (~1.8MB, L2-resident).
    const int lin = blockIdx.x;
    const int slice = lin & 7;
    const int b   = slice >> 1;
    const int ct  = slice & 1;
    const int jt  = lin >> 3;    // 0..63
    const int jbase = jt*64, cbase = ct*128;

    // K B-fragments: 4 j-frags, f16 hi/lo (persistent; 32 VGPR)
    f16x8 kfh[4], kfl[4];
    #pragma unroll
    for (int jf = 0; jf < 4; jf++) {
        size_t a = ((size_t)(b*NN + jbase + jf*16 + lr))*DD + lg*8;
        kfh[jf] = *(const f16x8*)(kh16 + a);
        kfl[jf] = *(const f16x8*)(kl16 + a);
    }

    const float* Sb = Sx + (size_t)b*NN;
    const _Float16* vb = v16 + (size_t)b*(NN/8)*CCH*8;

    const int i0 = wv*1024;     // this wave's i-quarter; 32 steps of 32

    // sigma-permuted q pointers: step A rows 8(lr>>2)+(lr&3), step B +4
    const int sigma = 8*(lr >> 2) + (lr & 3);
    const _Float16* qpA = q16 + ((size_t)(b*NN + i0 + sigma))*DD + lg*8;
    const _Float16* qpB = qpA + 4*DD;
    // s pointers follow sigma: lane lg covers i = 8lg+r (A), 8lg+4+r (B)
    const float* spA = Sb + i0 + 8*lg;
    const float* spB = spA + 4;
    // V B-frag: lane (lr,lg) reads 16B block ib = i0/8 + lg, c = ..+lr
    const _Float16* vp = vb + (((size_t)(i0/8 + lg)*CCH + cbase + lr) << 3);

    f32x4 acc[4][8] = {};   // [jf][cf] -- ONLY static subscripts below!

    #pragma clang loop unroll(disable)
    for (int s = 0; s < 32; ++s) {
        // loads for THIS step (L2-resident; TLP hides the latency)
        f16x8 qA = *(const f16x8*)qpA;  qpA += 32*DD;
        f16x8 qB = *(const f16x8*)qpB;  qpB += 32*DD;
        float4 sA4 = *(const float4*)spA; spA += 32;
        float4 sB4 = *(const float4*)spB; spB += 32;
        f16x8 vv[8];
        #pragma unroll
        for (int cf = 0; cf < 8; cf++)
            vv[cf] = *(const f16x8*)(vp + cf*128);
        vp += 32*CCH;

        #pragma unroll
        for (int jf = 0; jf < 4; jf++) {
            // QK for both sigma-halves (4 MFH, K=32)
            f32x4 eA = {};
            eA = MFH(qA, kfl[jf], eA);
            eA = MFH(qA, kfh[jf], eA);
            f32x4 eB = {};
            eB = MFH(qB, kfl[jf], eB);
            eB = MFH(qB, kfh[jf], eB);
            // exp + pack: concat of the two f16x4s IS the K=32 A-fragment
            union { f16x4 h4[2]; f16x8 h8; } pu;
            pu.h4[0] = pk4(vexp2(fmaf(eA[0], L2E, -sA4.x)),
                           vexp2(fmaf(eA[1], L2E, -sA4.y)),
                           vexp2(fmaf(eA[2], L2E, -sA4.z)),
                           vexp2(fmaf(eA[3], L2E, -sA4.w)));
            pu.h4[1] = pk4(vexp2(fmaf(eB[0], L2E, -sB4.x)),
                           vexp2(fmaf(eB[1], L2E, -sB4.y)),
                           vexp2(fmaf(eB[2], L2E, -sB4.z)),
                           vexp2(fmaf(eB[3], L2E, -sB4.w)));
            f16x8 pa = pu.h8;
            // PV: 8 full-rate K=32 MFMAs
            __builtin_amdgcn_s_setprio(1);
            #pragma unroll
            for (int cf = 0; cf < 8; cf++)
                acc[jf][cf] = MFH(pa, vv[cf], acc[jf][cf]);
            __builtin_amdgcn_s_setprio(0);
        }
    }

    // ------------- 3-barrier tree reduce over the 4 i-quarters -------------
    // All acc subscripts literal. slot(jf,cf) = (jf*8+cf)<<6 | lane.
    if (wv == 2) {
        #pragma unroll
        for (int jf = 0; jf < 4; jf++)
            #pragma unroll
            for (int cf = 0; cf < 8; cf++)
                Rb[((jf*8 + cf) << 6) + l] = acc[jf][cf];
    } else if (wv == 3) {
        #pragma unroll
        for (int jf = 0; jf < 4; jf++)
            #pragma unroll
            for (int cf = 0; cf < 8; cf++)
                Rb[2048 + ((jf*8 + cf) << 6) + l] = acc[jf][cf];
    }
    __syncthreads();
    if (wv == 0) {
        #pragma unroll
        for (int jf = 0; jf < 4; jf++)
            #pragma unroll
            for (int cf = 0; cf < 8; cf++)
                acc[jf][cf] += Rb[((jf*8 + cf) << 6) + l];
    } else if (wv == 1) {
        #pragma unroll
        for (int jf = 0; jf < 4; jf++)
            #pragma unroll
            for (int cf = 0; cf < 8; cf++)
                acc[jf][cf] += Rb[2048 + ((jf*8 + cf) << 6) + l];
    }
    __syncthreads();
    if (wv == 0) {          // gives jf {2,3} at base 0, slots {0,1}
        #pragma unroll
        for (int cf = 0; cf < 8; cf++) {
            Rb[((0*8 + cf) << 6) + l] = acc[2][cf];
            Rb[((1*8 + cf) << 6) + l] = acc[3][cf];
        }
    } else if (wv == 1) {   // gives jf {0,1} at base 2048, slots {0,1}
        #pragma unroll
        for (int cf = 0; cf < 8; cf++) {
            Rb[2048 + ((0*8 + cf) << 6) + l] = acc[0][cf];
            Rb[2048 + ((1*8 + cf) << 6) + l] = acc[1][cf];
        }
    }
    __syncthreads();

    const float gam = gamma[0];
    // Final: wv0 outputs jf {0,1} (reads wave1's halves at base 2048);
    //        wv1 outputs jf {2,3} (reads wave0's halves at base 0).
    if (wv == 0) {
        #pragma unroll
        for (int cf = 0; cf < 8; cf++) {
            {   // jf = 0 (wave1 stored at base 2048, slot 0)
                f32x4 o = Rb[2048 + ((0*8 + cf) << 6) + l];
                f32x4 a = acc[0][cf];
                a[0]+=o[0]; a[1]+=o[1]; a[2]+=o[2]; a[3]+=o[3];
                const int c = cbase + cf*16 + lr;
                const int j = jbase + 0*16 + lg*4;
                size_t off = ((size_t)(b*CCH + c))*NN + j;
                float4 xv = *(const float4*)(x + off);
                float4 ov;
                ov.x = fmaf(gam, a[0], xv.x);
                ov.y = fmaf(gam, a[1], xv.y);
                ov.z = fmaf(gam, a[2], xv.z);
                ov.w = fmaf(gam, a[3], xv.w);
                *(float4*)(out + off) = ov;
            }
            {   // jf = 1 (base 2048, slot 1)
                f32x4 o = Rb[2048 + ((1*8 + cf) << 6) + l];
                f32x4 a = acc[1][cf];
                a[0]+=o[0]; a[1]+=o[1]; a[2]+=o[2]; a[3]+=o[3];
                const int c = cbase + cf*16 + lr;
                const int j = jbase + 1*16 + lg*4;
                size_t off = ((size_t)(b*CCH + c))*NN + j;
                float4 xv = *(const float4*)(x + off);
                float4 ov;
                ov.x = fmaf(gam, a[0], xv.x);
                ov.y = fmaf(gam, a[1], xv.y);
                ov.z = fmaf(gam, a[2], xv.z);
                ov.w = fmaf(gam, a[3], xv.w);
                *(float4*)(out + off) = ov;
            }
        }
    } else if (wv == 1) {
        #pragma unroll
        for (int cf = 0; cf < 8; cf++) {
            {   // jf = 2 (wave0 stored at base 0, slot 0)
                f32x4 o = Rb[((0*8 + cf) << 6) + l];
                f32x4 a = acc[2][cf];
                a[0]+=o[0]; a[1]+=o[1]; a[2]+=o[2]; a[3]+=o[3];
                const int c = cbase + cf*16 + lr;
                const int j = jbase + 2*16 + lg*4;
                size_t off = ((size_t)(b*CCH + c))*NN + j;
                float4 xv = *(const float4*)(x + off);
                float4 ov;
                ov.x = fmaf(gam, a[0], xv.x);
                ov.y = fmaf(gam, a[1], xv.y);
                ov.z = fmaf(gam, a[2], xv.z);
                ov.w = fmaf(gam, a[3], xv.w);
                *(float4*)(out + off) = ov;
            }
            {   // jf = 3 (base 0, slot 1)
                f32x4 o = Rb[((1*8 + cf) << 6) + l];
                f32x4 a = acc[3][cf];
                a[0]+=o[0]; a[1]+=o[1]; a[2]+=o[2]; a[3]+=o[3];
                const int c = cbase + cf*16 + lr;
                const int j = jbase + 3*16 + lg*4;
                size_t off = ((size_t)(b*CCH + c))*NN + j;
                float4 xv = *(const float4*)(x + off);
                float4 ov;
                ov.x = fmaf(gam, a[0], xv.x);
                ov.y = fmaf(gam, a[1], xv.y);
                ov.z = fmaf(gam, a[2], xv.z);
                ov.w = fmaf(gam, a[3], xv.w);
                *(float4*)(out + off) = ov;
            }
        }
    }
}

// ---------------------------------------------------------------- launch
extern "C" void kernel_launch(void* const* d_in, const int* in_sizes, int n_in,
                              void* d_out, int out_size, void* d_ws, size_t ws_size,
                              hipStream_t stream)
{
    (void)in_sizes; (void)n_in; (void)out_size; (void)ws_size;
    const float* x     = (const float*)d_in[0];
    const float* wq    = (const float*)d_in[1];
    const float* bq    = (const float*)d_in[2];
    const float* wk    = (const float*)d_in[3];
    const float* bk    = (const float*)d_in[4];
    const float* wv    = (const float*)d_in[5];
    const float* bv    = (const float*)d_in[6];
    const float* gamma = (const float*)d_in[7];
    float* out = (float*)d_out;

    char* ws = (char*)d_ws;
    _Float16* q16  = (_Float16*)(ws + 0x000000);  // 1MB (f16 single)
    _Float16* k_hi = (_Float16*)(ws + 0x100000);  // 1MB (f16 hi)
    _Float16* k_lo = (_Float16*)(ws + 0x200000);  // 1MB (f16 lo)
    _Float16* v16  = (_Float16*)(ws + 0x400000);  // 8MB blocked
    float*    Zp   = (float*)   (ws + 0xC00000);  // 128KB partials
    float*    Sx   = (float*)   (ws + 0xC20000);  // 64KB (SL)

    proj_qk<<<dim3(64, 4),    256, 0, stream>>>(x, wq, bq, wk, bk,
                                                q16, k_hi, k_lo);
    proj_v <<<dim3(2, 64, 4), 512, 0, stream>>>(x, wv, bv, v16);
    stats_kernel  <<<dim3(64, 2, 4), 512, 0, stream>>>(q16, k_hi, k_lo, Zp);
    combine_kernel<<<dim3(64),       256, 0, stream>>>(Zp, Sx);
    attn_kernel   <<<dim3(512),      256, 0, stream>>>(
        q16, k_hi, k_lo, v16, Sx, x, gamma, out);
}